// Round 10
// baseline (272.631 us; speedup 1.0000x reference)
//
#include <hip/hip_runtime.h>

// EWMA scan y_t = (1-a)*y_{t-1} + a*x_t as a single-pass decoupled-lookback
// chunked scan (R2 structure, which validated correct, with the spill bug
// fixed: __launch_bounds__(256,4) lets z[64] live in VGPRs; R2's 52-VGPR
// build spilled it to scratch -> 268us).
// One kernel: read data once (134MB), write out once (134MB).
// Chunk = 64 rows x 256 cols; 4 column-group chains of 512 chunks.

#define LT   32768
#define DC   1024
#define TCH  64
#define CCH  (LT / TCH)       // 512 chunks per chain
#define NG   4                // column groups (chains)
#define CW   256              // columns per group = threads per block
#define NBLK (CCH * NG)       // 2048 blocks

__device__ __forceinline__ void st_ws(float* p, float v) {
    __hip_atomic_store(p, v, __ATOMIC_RELAXED, __HIP_MEMORY_SCOPE_AGENT);
}
__device__ __forceinline__ float ld_ws(const float* p) {
    return __hip_atomic_load(p, __ATOMIC_RELAXED, __HIP_MEMORY_SCOPE_AGENT);
}

__global__ void ewma_clear(unsigned* __restrict__ w, int n) {
    int i = blockIdx.x * blockDim.x + threadIdx.x;
    if (i < n)
        __hip_atomic_store(&w[i], 0u, __ATOMIC_RELAXED, __HIP_MEMORY_SCOPE_AGENT);
}

__global__ __launch_bounds__(CW, 4)
void ewma_scan(const float* __restrict__ data,
               const float* __restrict__ first,
               const float* __restrict__ alpha_p,
               float* __restrict__ out,
               unsigned* __restrict__ ticket,
               unsigned* __restrict__ flags,
               float* __restrict__ agg,
               float* __restrict__ pref) {
    __shared__ unsigned s_bid;
    __shared__ int s_n;
    __shared__ int s_pref;
    const int tid = threadIdx.x;
    if (tid == 0) s_bid = atomicAdd(ticket, 1u);
    __syncthreads();
    const unsigned vb = s_bid;
    const int c = (int)(vb >> 2);        // chunk (ticket order => waits only on earlier tickets)
    const int g = (int)(vb & 3u);        // column group
    const int col = g * CW + tid;
    const int chain = g * CCH;

    const float alpha = alpha_p[0];
    const float decay = 1.0f - alpha;
    float rT = decay;                    // decay^64 via 6 squarings
    rT *= rT; rT *= rT; rT *= rT; rT *= rT; rT *= rT; rT *= rT;

    // ---- local zero-init scan, held in registers (needs ~100 VGPR) ----
    const float* p = data + (size_t)c * TCH * DC + col;
    float z[TCH];
    float zz = 0.f;
#pragma unroll
    for (int i = 0; i < TCH; ++i) {
        zz = fmaf(decay, zz, alpha * p[(size_t)i * DC]);
        z[i] = zz;
    }

    // ---- publish aggregate (chunk-local end value) ----
    if (c > 0 && c < CCH - 1) {
        st_ws(&agg[(size_t)(chain + c) * CW + tid], zz);
        __syncthreads();   // payload stores drained before flag
        if (tid == 0)
            __hip_atomic_store(&flags[chain + c], 1u, __ATOMIC_RELEASE,
                               __HIP_MEMORY_SCOPE_AGENT);
    }

    // ---- resolve carry (y entering this chunk) via 64-wide lookback ----
    float carry;
    if (c == 0) {
        carry = first[col];
    } else {
        carry = 0.f;
        float rp = 1.f;
        int j = c - 1;                   // next predecessor chunk to consume
        for (;;) {
            if (tid < 64) {
                int jj = j - tid;
                unsigned f = 0u;
                if (jj >= 0)
                    f = __hip_atomic_load(&flags[chain + jj], __ATOMIC_ACQUIRE,
                                          __HIP_MEMORY_SCOPE_AGENT);
                unsigned long long live = __ballot(f != 0u);
                unsigned long long prm  = __ballot(f == 2u);
                if (tid == 0) {
                    unsigned long long notlive = ~live;
                    int run    = (notlive == 0ull) ? 64 : (__ffsll((long long)notlive) - 1);
                    int pfirst = (prm == 0ull) ? 64 : (__ffsll((long long)prm) - 1);
                    if (pfirst < run) { s_n = pfirst + 1; s_pref = 1; }
                    else             { s_n = run;        s_pref = 0; }
                }
            }
            __syncthreads();
            const int n  = s_n;
            const int hp = s_pref;
            __syncthreads();
            if (n == 0) { __builtin_amdgcn_s_sleep(2); continue; }
            for (int k = 0; k < n; ++k) {
                const float* src = (hp && k == n - 1) ? pref : agg;
                float v = ld_ws(&src[(size_t)(chain + j - k) * CW + tid]);
                carry = fmaf(rp, v, carry);
                rp *= rT;
            }
            j -= n;
            if (hp) break;
        }
    }

    // ---- publish inclusive prefix (true y at chunk end) ----
    if (c < CCH - 1) {
        float y_end = fmaf(rT, carry, zz);
        st_ws(&pref[(size_t)(chain + c) * CW + tid], y_end);
        __syncthreads();
        if (tid == 0)
            __hip_atomic_store(&flags[chain + c], 2u, __ATOMIC_RELEASE,
                               __HIP_MEMORY_SCOPE_AGENT);
    }

    // ---- write outputs: y_i = z_i + decay^(i+1) * carry ----
    float* o = out + (size_t)c * TCH * DC + col;
    float w = decay;
    float y = 0.f;
#pragma unroll
    for (int i = 0; i < TCH; ++i) {
        y = fmaf(w, carry, z[i]);
        o[(size_t)i * DC] = y;
        w *= decay;
    }
    if (c == CCH - 1)
        out[(size_t)LT * DC + col] = y;   // last-row output
}

extern "C" void kernel_launch(void* const* d_in, const int* in_sizes, int n_in,
                              void* d_out, int out_size, void* d_ws, size_t ws_size,
                              hipStream_t stream) {
    const float* data    = (const float*)d_in[0];
    const float* first   = (const float*)d_in[1];
    const float* alpha_p = (const float*)d_in[2];
    float* out = (float*)d_out;

    float* agg  = (float*)d_ws;                         // NG*CCH*CW floats (2 MB)
    float* pref = agg + (size_t)NG * CCH * CW;          // 2 MB
    unsigned* flags  = (unsigned*)(pref + (size_t)NG * CCH * CW);  // NG*CCH
    unsigned* ticket = flags + NG * CCH;                 // 1

    const int nclear = NG * CCH + 1;
    ewma_clear<<<(nclear + 255) / 256, 256, 0, stream>>>(flags, nclear);

    ewma_scan<<<NBLK, CW, 0, stream>>>(
        data, first, alpha_p, out, ticket, flags, agg, pref);
}